// Round 3
// baseline (476.024 us; speedup 1.0000x reference)
//
#include <hip/hip_runtime.h>
#include <hip/hip_bf16.h>

// ---------------- problem constants ----------------
#define HE   12
#define HD   64
#define Cc   768
#define C2   1536
#define C4   3072
#define N7   5376
#define Bb   2
#define Ss   2048      // H*W*D = 16*16*8
#define BSr  4096      // B*S rows
#define PI_F 3.14159265358979f

using f32x4  = __attribute__((ext_vector_type(4))) float;
using short8 = __attribute__((ext_vector_type(8))) short;

__device__ __forceinline__ unsigned short f2b(float f) {
    union { float f; unsigned int u; } v; v.f = f;
    unsigned int u = v.u;
    unsigned int r = (u + 0x7fffu + ((u >> 16) & 1u)) >> 16;
    return (unsigned short)r;
}
__device__ __forceinline__ float b2f(unsigned short s) {
    union { unsigned int u; float f; } v; v.u = ((unsigned int)s) << 16;
    return v.f;
}
__device__ __forceinline__ f32x4 mfma16(short8 a, short8 b, f32x4 c) {
    return __builtin_amdgcn_mfma_f32_16x16x32_bf16(a, b, c, 0, 0, 0);
}

union U8 { uint4 v; unsigned short u[8]; };

// ---------------- 1. tiled transpose f32 -> bf16 (weights) ----------------
// src (R, Ccol) row-major f32  ->  dst (Ccol, R) row-major bf16
__global__ __launch_bounds__(256) void transpose_w(const float* __restrict__ src,
                                                   unsigned short* __restrict__ dst,
                                                   int R, int Ccol) {
    __shared__ float tile[32][33];
    int tx = threadIdx.x & 31, ty = threadIdx.x >> 5;
    int rt = blockIdx.y * 32, ct = blockIdx.x * 32;
#pragma unroll
    for (int i = 0; i < 4; ++i)
        tile[ty + i * 8][tx] = src[(size_t)(rt + ty + i * 8) * Ccol + ct + tx];
    __syncthreads();
#pragma unroll
    for (int i = 0; i < 4; ++i)
        dst[(size_t)(ct + ty + i * 8) * R + rt + tx] = f2b(tile[tx][ty + i * 8]);
}

// ---------------- 2. groupnorm stats: 24 blocks, each 131072 contiguous f32 ----
__global__ __launch_bounds__(256) void gn_stats(const float* __restrict__ x,
                                                float* __restrict__ stat) {
    int j = blockIdx.x;  // b*12+g : channels are contiguous -> contiguous slab
    const float4* p = (const float4*)(x + (size_t)j * 131072);
    float s = 0.f, ss = 0.f;
    for (int i = threadIdx.x; i < 32768; i += 256) {
        float4 v = p[i];
        s  += v.x + v.y + v.z + v.w;
        ss += v.x * v.x + v.y * v.y + v.z * v.z + v.w * v.w;
    }
#pragma unroll
    for (int m = 1; m < 64; m <<= 1) { s += __shfl_xor(s, m); ss += __shfl_xor(ss, m); }
    __shared__ float ls[4], lss[4];
    int wid = threadIdx.x >> 6;
    if ((threadIdx.x & 63) == 0) { ls[wid] = s; lss[wid] = ss; }
    __syncthreads();
    if (threadIdx.x == 0) {
        s = ls[0] + ls[1] + ls[2] + ls[3];
        ss = lss[0] + lss[1] + lss[2] + lss[3];
        float mu  = s / 131072.0f;
        float var = ss / 131072.0f - mu * mu;
        stat[j * 2]     = mu;
        stat[j * 2 + 1] = rsqrtf(var + 1e-5f);
    }
}

// ---------------- 3. normalize + transpose (B,C,S) -> t bf16 (B*S, C) ----------
__global__ __launch_bounds__(256) void norm_transpose(const float* __restrict__ x,
                                                      const float* __restrict__ stat,
                                                      const float* __restrict__ w,
                                                      const float* __restrict__ bgn,
                                                      unsigned short* __restrict__ t) {
    __shared__ float tile[32][33];
    int b = blockIdx.z;
    int st = blockIdx.x * 32, ct = blockIdx.y * 32;
    int tx = threadIdx.x & 31, ty = threadIdx.x >> 5;
#pragma unroll
    for (int i = 0; i < 4; ++i) {
        int c = ct + ty + i * 8;
        int g = c >> 6;
        float mu = stat[(b * 12 + g) * 2], rs = stat[(b * 12 + g) * 2 + 1];
        float v = x[(size_t)(b * Cc + c) * Ss + st + tx];
        tile[ty + i * 8][tx] = (v - mu) * rs * w[c] + bgn[c];
    }
    __syncthreads();
#pragma unroll
    for (int i = 0; i < 4; ++i) {
        int s = st + ty + i * 8, c = ct + tx;
        t[(size_t)(b * Ss + s) * Cc + c] = f2b(tile[tx][ty + i * 8]);
    }
}

// ---------------- 4. generic 128x128x32 bf16 MFMA GEMM ----------------
// C(M,N) = A(M,K)bf16 @ Bt(N,K)bf16^T  [+ bias] [+= existing f32 C]
template<bool ACCUM, bool BIAS, bool OUTBF16>
__global__ __launch_bounds__(256) void gemm128(const unsigned short* __restrict__ A,
                                               const unsigned short* __restrict__ Bt,
                                               const float* __restrict__ bias,
                                               void* __restrict__ Cout,
                                               int M, int N, int K) {
    __shared__ __align__(16) unsigned short As[128][40];
    __shared__ __align__(16) unsigned short Bs[128][40];
    const int tid = threadIdx.x;
    const int wid = tid >> 6, lane = tid & 63;
    const int lr = lane & 15, lh = lane >> 4;
    const int wr = wid >> 1, wc = wid & 1;
    const int row0 = blockIdx.y * 128, col0 = blockIdx.x * 128;
    f32x4 acc[4][4] = {};

    for (int k0 = 0; k0 < K; k0 += 32) {
#pragma unroll
        for (int i = 0; i < 2; ++i) {
            int o = tid + i * 256;              // 0..511
            int r = o >> 2, kc = (o & 3) * 8;
            *(uint4*)&As[r][kc] = *(const uint4*)&A [(size_t)(row0 + r) * K + k0 + kc];
            *(uint4*)&Bs[r][kc] = *(const uint4*)&Bt[(size_t)(col0 + r) * K + k0 + kc];
        }
        __syncthreads();
        short8 af[4], bfr[4];
#pragma unroll
        for (int m = 0; m < 4; ++m) af[m]  = *(const short8*)&As[wr * 64 + m * 16 + lr][lh * 8];
#pragma unroll
        for (int n = 0; n < 4; ++n) bfr[n] = *(const short8*)&Bs[wc * 64 + n * 16 + lr][lh * 8];
#pragma unroll
        for (int m = 0; m < 4; ++m)
#pragma unroll
            for (int n = 0; n < 4; ++n)
                acc[m][n] = mfma16(af[m], bfr[n], acc[m][n]);
        __syncthreads();
    }

#pragma unroll
    for (int m = 0; m < 4; ++m)
#pragma unroll
        for (int n = 0; n < 4; ++n) {
            int row = row0 + wr * 64 + m * 16 + lh * 4;
            int col = col0 + wc * 64 + n * 16 + lr;
            float bv = BIAS ? bias[col] : 0.0f;
#pragma unroll
            for (int r = 0; r < 4; ++r) {
                size_t idx = (size_t)(row + r) * N + col;
                float v = acc[m][n][r] + bv;
                if (ACCUM) v += ((const float*)Cout)[idx];
                if (OUTBF16) ((unsigned short*)Cout)[idx] = f2b(v);
                else         ((float*)Cout)[idx] = v;
            }
        }
}

// ---------------- 5. per-(b,s,head) LN + RoPE on q,k ; copy v ----------------
__global__ __launch_bounds__(256) void qkv_prep(const unsigned short* __restrict__ fused,
                                                const float* __restrict__ qnw, const float* __restrict__ qnb,
                                                const float* __restrict__ knw, const float* __restrict__ knb,
                                                unsigned short* __restrict__ qf,
                                                unsigned short* __restrict__ kf,
                                                unsigned short* __restrict__ vf) {
    const int wid = threadIdx.x >> 6, lane = threadIdx.x & 63;
    const int job = blockIdx.x * 4 + wid;          // 0 .. B*S*HE-1
    const int srow = job / 12, h = job % 12;       // srow = b*2048+s
    const int b = srow >> 11, s = srow & 2047;

    size_t base = (size_t)srow * N7 + C4 + h * HD;
    float qv = b2f(fused[base + lane]);
    float kv = b2f(fused[base + Cc + lane]);
    float vv = b2f(fused[base + 2 * Cc + lane]);

    // layernorm over 64 lanes
    float qs = qv, ks = kv;
#pragma unroll
    for (int m = 1; m < 64; m <<= 1) { qs += __shfl_xor(qs, m); ks += __shfl_xor(ks, m); }
    float qmu = qs * (1.0f / 64.0f), kmu = ks * (1.0f / 64.0f);
    float qd = qv - qmu, kd = kv - kmu;
    float qv2 = qd * qd, kv2 = kd * kd;
#pragma unroll
    for (int m = 1; m < 64; m <<= 1) { qv2 += __shfl_xor(qv2, m); kv2 += __shfl_xor(kv2, m); }
    float qn = qd * rsqrtf(qv2 * (1.0f / 64.0f) + 1e-5f) * qnw[lane] + qnb[lane];
    float kn = kd * rsqrtf(kv2 * (1.0f / 64.0f) + 1e-5f) * knw[lane] + knb[lane];

    // axial rope on first 48 dims (pairs never straddle the branch)
    if (lane < 48) {
        int axis = lane >> 4, ii = (lane & 15) >> 1;
        float basef = (1.0f + (float)ii * (127.0f / 7.0f)) * PI_F;
        int   pos_i = (axis == 0) ? (s >> 7) : (axis == 1) ? ((s >> 3) & 15) : (s & 7);
        float denom = (axis == 2) ? 7.0f : 15.0f;
        float pos   = -1.0f + 2.0f * (float)pos_i / denom;
        float ang   = pos * basef;
        float sn, cs;
        sincosf(ang, &sn, &cs);
        float qp = __shfl_xor(qn, 1);
        float kp = __shfl_xor(kn, 1);
        qn = (lane & 1) ? (qn * cs + qp * sn) : (qn * cs - qp * sn);
        kn = (lane & 1) ? (kn * cs + kp * sn) : (kn * cs - kp * sn);
    }

    size_t obase = ((size_t)(b * 12 + h) * Ss + s) * HD + lane;
    qf[obase] = f2b(qn);
    kf[obase] = f2b(kn);
    vf[obase] = f2b(vv);
}

// ---------------- 6. ffa = silu(gate) * xh  (bf16 in/out) ----------------
__global__ __launch_bounds__(256) void ffa_prep(const unsigned short* __restrict__ fused,
                                                unsigned short* __restrict__ ffa) {
    int i8 = blockIdx.x * 256 + threadIdx.x;    // 786432 octets
    int row = i8 / 192, co = (i8 % 192) * 8;
    U8 xa, ga, oa;
    xa.v = *(const uint4*)&fused[(size_t)row * N7 + co];
    ga.v = *(const uint4*)&fused[(size_t)row * N7 + C2 + co];
#pragma unroll
    for (int j = 0; j < 8; ++j) {
        float g = b2f(ga.u[j]);
        float xh = b2f(xa.u[j]);
        float sg = 1.0f / (1.0f + expf(-g));
        oa.u[j] = f2b(g * sg * xh);
    }
    *(uint4*)&ffa[(size_t)row * C2 + co] = oa.v;
}

// ---------------- 7. flash attention: per (b,h), 64 q-rows / block ----------------
__global__ __launch_bounds__(256) void attn64(const unsigned short* __restrict__ qf,
                                              const unsigned short* __restrict__ kf,
                                              const unsigned short* __restrict__ vf,
                                              unsigned short* __restrict__ att) {
    __shared__ __align__(16) unsigned short Ks[64][72];
    __shared__ __align__(16) unsigned short Vt[64][72];   // Vt[hd][key]
    __shared__ __align__(16) unsigned short Ps[4][16][72];
    const int tid = threadIdx.x, wid = tid >> 6, lane = tid & 63;
    const int lr = lane & 15, lh = lane >> 4;
    const int bh = blockIdx.y, qt = blockIdx.x;
    const int b = bh / 12, h = bh % 12;
    const size_t kvbase = (size_t)bh * Ss * HD;

    const int qrow = qt * 64 + wid * 16 + lr;
    short8 qa0 = *(const short8*)&qf[kvbase + (size_t)qrow * HD + lh * 8];
    short8 qa1 = *(const short8*)&qf[kvbase + (size_t)qrow * HD + 32 + lh * 8];

    float m_run[4] = {-1e30f, -1e30f, -1e30f, -1e30f};
    float l_run[4] = {0.f, 0.f, 0.f, 0.f};
    f32x4 oacc[4] = {};

    for (int kt = 0; kt < 32; ++kt) {
        // stage K tile (row-major) and V tile (transposed)
#pragma unroll
        for (int i = 0; i < 2; ++i) {
            int o = tid + i * 256;               // 0..511
            int r = o >> 3, kc = (o & 7) * 8;
            *(uint4*)&Ks[r][kc] = *(const uint4*)&kf[kvbase + (size_t)(kt * 64 + r) * HD + kc];
            U8 vv; vv.v = *(const uint4*)&vf[kvbase + (size_t)(kt * 64 + r) * HD + kc];
#pragma unroll
            for (int j = 0; j < 8; ++j) Vt[kc + j][r] = vv.u[j];
        }
        __syncthreads();

        // scores: 16 q-rows x 64 keys per wave
        f32x4 sc[4];
#pragma unroll
        for (int n = 0; n < 4; ++n) {
            f32x4 z = {0.f, 0.f, 0.f, 0.f};
            short8 k0 = *(const short8*)&Ks[n * 16 + lr][lh * 8];
            short8 k1 = *(const short8*)&Ks[n * 16 + lr][32 + lh * 8];
            z = mfma16(qa0, k0, z);
            z = mfma16(qa1, k1, z);
            sc[n] = z;
        }

        // online softmax per row (rows live in lh-group x reg)
#pragma unroll
        for (int r = 0; r < 4; ++r) {
            float s0 = sc[0][r] * 0.125f, s1 = sc[1][r] * 0.125f;
            float s2 = sc[2][r] * 0.125f, s3 = sc[3][r] * 0.125f;
            float tm = fmaxf(fmaxf(s0, s1), fmaxf(s2, s3));
#pragma unroll
            for (int mm = 1; mm < 16; mm <<= 1) tm = fmaxf(tm, __shfl_xor(tm, mm));
            float mnew = fmaxf(m_run[r], tm);
            float corr = expf(m_run[r] - mnew);
            float p0 = expf(s0 - mnew), p1 = expf(s1 - mnew);
            float p2 = expf(s2 - mnew), p3 = expf(s3 - mnew);
            float ps = p0 + p1 + p2 + p3;
#pragma unroll
            for (int mm = 1; mm < 16; mm <<= 1) ps += __shfl_xor(ps, mm);
            l_run[r] = l_run[r] * corr + ps;
            m_run[r] = mnew;
#pragma unroll
            for (int n = 0; n < 4; ++n) oacc[n][r] *= corr;
            int prow = lh * 4 + r;
            Ps[wid][prow][lr]      = f2b(p0);
            Ps[wid][prow][16 + lr] = f2b(p1);
            Ps[wid][prow][32 + lr] = f2b(p2);
            Ps[wid][prow][48 + lr] = f2b(p3);
        }

        // PV: out(16x64) += P(16x64) @ V(64x64)
        short8 pa0 = *(const short8*)&Ps[wid][lr][lh * 8];
        short8 pa1 = *(const short8*)&Ps[wid][lr][32 + lh * 8];
#pragma unroll
        for (int n = 0; n < 4; ++n) {
            short8 v0 = *(const short8*)&Vt[n * 16 + lr][lh * 8];
            short8 v1 = *(const short8*)&Vt[n * 16 + lr][32 + lh * 8];
            oacc[n] = mfma16(pa0, v0, oacc[n]);
            oacc[n] = mfma16(pa1, v1, oacc[n]);
        }
        __syncthreads();
    }

    // write att (B*S, C) bf16 at col h*64+...
#pragma unroll
    for (int n = 0; n < 4; ++n)
#pragma unroll
        for (int r = 0; r < 4; ++r) {
            int srow_w = qt * 64 + wid * 16 + lh * 4 + r;
            int col = h * HD + n * 16 + lr;
            att[(size_t)(b * Ss + srow_w) * Cc + col] = f2b(oacc[n][r] / l_run[r]);
        }
}

// ---------------- 8. final: out = gamma*oacc^T + x  ((B*S,C) -> (B,C,S)) -------
__global__ __launch_bounds__(256) void final_out(const float* __restrict__ oacc,
                                                 const float* __restrict__ x,
                                                 const float* __restrict__ gamma,
                                                 float* __restrict__ out) {
    __shared__ float tile[32][33];
    int b = blockIdx.z;
    int st = blockIdx.x * 32, ct = blockIdx.y * 32;
    int tx = threadIdx.x & 31, ty = threadIdx.x >> 5;
#pragma unroll
    for (int i = 0; i < 4; ++i) {
        int s = st + ty + i * 8;
        tile[ty + i * 8][tx] = oacc[(size_t)(b * Ss + s) * Cc + ct + tx];
    }
    __syncthreads();
#pragma unroll
    for (int i = 0; i < 4; ++i) {
        int c = ct + ty + i * 8;
        size_t idx = (size_t)(b * Cc + c) * Ss + st + tx;
        out[idx] = gamma[c] * tile[tx][ty + i * 8] + x[idx];
    }
}

// ---------------- host launch ----------------
extern "C" void kernel_launch(void* const* d_in, const int* in_sizes, int n_in,
                              void* d_out, int out_size, void* d_ws, size_t ws_size,
                              hipStream_t stream) {
    const float* x     = (const float*)d_in[0];
    const float* n1w   = (const float*)d_in[1];
    const float* n1b   = (const float*)d_in[2];
    const float* gamma = (const float*)d_in[3];
    const float* Wf    = (const float*)d_in[4];
    const float* bfu   = (const float*)d_in[5];
    const float* qnw   = (const float*)d_in[6];
    const float* qnb   = (const float*)d_in[7];
    const float* knw   = (const float*)d_in[8];
    const float* knb   = (const float*)d_in[9];
    const float* Wa    = (const float*)d_in[10];
    const float* Wo    = (const float*)d_in[11];
    const float* bo    = (const float*)d_in[12];

    char* ws = (char*)d_ws;
    size_t off = 0;
    auto alloc = [&](size_t bytes) {
        char* p = ws + off;
        off = (off + bytes + 255) & ~(size_t)255;
        return p;
    };
    // t is dead after the fused GEMM -> attB aliases it (same size).
    // fused is dead after qkv_prep+ffa_prep -> oacc aliases its front.
    float*          stat  = (float*)alloc(24 * 2 * 4);
    unsigned short* t     = (unsigned short*)alloc((size_t)BSr * Cc * 2);
    unsigned short* WtF   = (unsigned short*)alloc((size_t)N7 * Cc * 2);
    unsigned short* fused = (unsigned short*)alloc((size_t)BSr * N7 * 2);
    unsigned short* qfB   = (unsigned short*)alloc((size_t)Bb * HE * Ss * HD * 2);
    unsigned short* kfB   = (unsigned short*)alloc((size_t)Bb * HE * Ss * HD * 2);
    unsigned short* vfB   = (unsigned short*)alloc((size_t)Bb * HE * Ss * HD * 2);
    unsigned short* ffa   = (unsigned short*)alloc((size_t)BSr * C2 * 2);
    unsigned short* WtA   = (unsigned short*)alloc((size_t)Cc * Cc * 2);
    unsigned short* WtO   = (unsigned short*)alloc((size_t)Cc * C2 * 2);
    unsigned short* attB  = t;                       // alias (t dead by then)
    float*          oacc  = (float*)fused;           // alias (fused dead by then)

    // weights -> transposed bf16
    transpose_w<<<dim3(N7 / 32, Cc / 32), 256, 0, stream>>>(Wf, WtF, Cc, N7);
    transpose_w<<<dim3(Cc / 32, Cc / 32), 256, 0, stream>>>(Wa, WtA, Cc, Cc);
    transpose_w<<<dim3(Cc / 32, C2 / 32), 256, 0, stream>>>(Wo, WtO, C2, Cc);

    gn_stats<<<24, 256, 0, stream>>>(x, stat);
    norm_transpose<<<dim3(Ss / 32, Cc / 32, Bb), 256, 0, stream>>>(x, stat, n1w, n1b, t);

    // fused = t @ W_fused + b_fused   (bf16 out)
    gemm128<false, true, true><<<dim3(N7 / 128, BSr / 128), 256, 0, stream>>>(
        t, WtF, bfu, fused, BSr, N7, Cc);

    qkv_prep<<<(Bb * Ss * HE) / 4, 256, 0, stream>>>(fused, qnw, qnb, knw, knb, qfB, kfB, vfB);
    ffa_prep<<<(BSr * C2 / 8) / 256, 256, 0, stream>>>(fused, ffa);

    attn64<<<dim3(Ss / 64, Bb * HE), 256, 0, stream>>>(qfB, kfB, vfB, attB);

    // oacc = att @ W_attn ; oacc += ffa @ W_ffout + b_ffout
    gemm128<false, false, false><<<dim3(Cc / 128, BSr / 128), 256, 0, stream>>>(
        attB, WtA, nullptr, oacc, BSr, Cc, Cc);
    gemm128<true, true, false><<<dim3(Cc / 128, BSr / 128), 256, 0, stream>>>(
        ffa, WtO, bo, oacc, BSr, Cc, C2);

    final_out<<<dim3(Ss / 32, Cc / 32, Bb), 256, 0, stream>>>(oacc, x, gamma, (float*)d_out);
}

// Round 4
// 419.241 us; speedup vs baseline: 1.1354x; 1.1354x over previous
//
#include <hip/hip_runtime.h>
#include <hip/hip_bf16.h>

// ---------------- problem constants ----------------
#define HE   12
#define HD   64
#define Cc   768
#define C2   1536
#define C4   3072
#define N7   5376
#define Bb   2
#define Ss   2048      // H*W*D = 16*16*8
#define BSr  4096      // B*S rows
#define PI_F 3.14159265358979f

using f32x4  = __attribute__((ext_vector_type(4))) float;
using short8 = __attribute__((ext_vector_type(8))) short;

__device__ __forceinline__ unsigned short f2b(float f) {
    union { float f; unsigned int u; } v; v.f = f;
    unsigned int u = v.u;
    unsigned int r = (u + 0x7fffu + ((u >> 16) & 1u)) >> 16;
    return (unsigned short)r;
}
__device__ __forceinline__ unsigned short f2bt(float f) {   // truncating (P values in [0,e^0])
    union { float f; unsigned int u; } v; v.f = f;
    return (unsigned short)(v.u >> 16);
}
__device__ __forceinline__ float b2f(unsigned short s) {
    union { unsigned int u; float f; } v; v.u = ((unsigned int)s) << 16;
    return v.f;
}
__device__ __forceinline__ f32x4 mfma16(short8 a, short8 b, f32x4 c) {
    return __builtin_amdgcn_mfma_f32_16x16x32_bf16(a, b, c, 0, 0, 0);
}
// async global->LDS, 16 B per lane. LDS dest resolves to wave-uniform base + lane*16.
__device__ __forceinline__ void gl_lds16(const unsigned short* g, unsigned short* l) {
    __builtin_amdgcn_global_load_lds(
        (const __attribute__((address_space(1))) unsigned int*)(const void*)g,
        (__attribute__((address_space(3))) unsigned int*)(void*)l, 16, 0, 0);
}

union U8 { uint4 v; unsigned short u[8]; };

// ---------------- 1. tiled transpose f32 -> bf16 (weights) ----------------
__global__ __launch_bounds__(256) void transpose_w(const float* __restrict__ src,
                                                   unsigned short* __restrict__ dst,
                                                   int R, int Ccol) {
    __shared__ float tile[32][33];
    int tx = threadIdx.x & 31, ty = threadIdx.x >> 5;
    int rt = blockIdx.y * 32, ct = blockIdx.x * 32;
#pragma unroll
    for (int i = 0; i < 4; ++i)
        tile[ty + i * 8][tx] = src[(size_t)(rt + ty + i * 8) * Ccol + ct + tx];
    __syncthreads();
#pragma unroll
    for (int i = 0; i < 4; ++i)
        dst[(size_t)(ct + ty + i * 8) * R + rt + tx] = f2b(tile[tx][ty + i * 8]);
}

// ---------------- 2. groupnorm stats ----------------
__global__ __launch_bounds__(256) void gn_stats(const float* __restrict__ x,
                                                float* __restrict__ stat) {
    int j = blockIdx.x;
    const float4* p = (const float4*)(x + (size_t)j * 131072);
    float s = 0.f, ss = 0.f;
    for (int i = threadIdx.x; i < 32768; i += 256) {
        float4 v = p[i];
        s  += v.x + v.y + v.z + v.w;
        ss += v.x * v.x + v.y * v.y + v.z * v.z + v.w * v.w;
    }
#pragma unroll
    for (int m = 1; m < 64; m <<= 1) { s += __shfl_xor(s, m); ss += __shfl_xor(ss, m); }
    __shared__ float ls[4], lss[4];
    int wid = threadIdx.x >> 6;
    if ((threadIdx.x & 63) == 0) { ls[wid] = s; lss[wid] = ss; }
    __syncthreads();
    if (threadIdx.x == 0) {
        s = ls[0] + ls[1] + ls[2] + ls[3];
        ss = lss[0] + lss[1] + lss[2] + lss[3];
        float mu  = s / 131072.0f;
        float var = ss / 131072.0f - mu * mu;
        stat[j * 2]     = mu;
        stat[j * 2 + 1] = rsqrtf(var + 1e-5f);
    }
}

// ---------------- 3. normalize + transpose (B,C,S) -> t bf16 (B*S, C) ----------
__global__ __launch_bounds__(256) void norm_transpose(const float* __restrict__ x,
                                                      const float* __restrict__ stat,
                                                      const float* __restrict__ w,
                                                      const float* __restrict__ bgn,
                                                      unsigned short* __restrict__ t) {
    __shared__ float tile[32][33];
    int b = blockIdx.z;
    int st = blockIdx.x * 32, ct = blockIdx.y * 32;
    int tx = threadIdx.x & 31, ty = threadIdx.x >> 5;
#pragma unroll
    for (int i = 0; i < 4; ++i) {
        int c = ct + ty + i * 8;
        int g = c >> 6;
        float mu = stat[(b * 12 + g) * 2], rs = stat[(b * 12 + g) * 2 + 1];
        float v = x[(size_t)(b * Cc + c) * Ss + st + tx];
        tile[ty + i * 8][tx] = (v - mu) * rs * w[c] + bgn[c];
    }
    __syncthreads();
#pragma unroll
    for (int i = 0; i < 4; ++i) {
        int s = st + ty + i * 8, c = ct + tx;
        t[(size_t)(b * Ss + s) * Cc + c] = f2b(tile[tx][ty + i * 8]);
    }
}

// ---------------- 4. 128x128x32 bf16 MFMA GEMM, global_load_lds staging ---------
// C(M,N) = A(M,K)bf16 @ Bt(N,K)bf16^T  [+ bias] [+= existing f32 C]
// Linear [128][32] LDS tiles: staging writes and fragment reads are bank-minimal.
template<bool ACCUM, bool BIAS, bool OUTBF16>
__global__ __launch_bounds__(256) void gemm128(const unsigned short* __restrict__ A,
                                               const unsigned short* __restrict__ Bt,
                                               const float* __restrict__ bias,
                                               void* __restrict__ Cout,
                                               int M, int N, int K) {
    __shared__ __align__(16) unsigned short As[128 * 32];
    __shared__ __align__(16) unsigned short Bs[128 * 32];
    const int tid = threadIdx.x;
    const int wid = tid >> 6, lane = tid & 63;
    const int lr = lane & 15, lh = lane >> 4;
    const int wr = wid >> 1, wc = wid & 1;
    const int row0 = blockIdx.y * 128, col0 = blockIdx.x * 128;
    // thread o stages As elems [o*8, o*8+8) = row o>>2, kcols (o&3)*8..+8
    const unsigned short* ga = A  + (size_t)(row0 + (tid >> 2)) * K + (tid & 3) * 8;
    const unsigned short* gb = Bt + (size_t)(col0 + (tid >> 2)) * K + (tid & 3) * 8;
    f32x4 acc[4][4] = {};

    for (int k0 = 0; k0 < K; k0 += 32) {
        gl_lds16(ga + k0,          &As[tid * 8]);
        gl_lds16(ga + 64 * K + k0, &As[2048 + tid * 8]);
        gl_lds16(gb + k0,          &Bs[tid * 8]);
        gl_lds16(gb + 64 * K + k0, &Bs[2048 + tid * 8]);
        __syncthreads();
        short8 af[4], bfr[4];
#pragma unroll
        for (int m = 0; m < 4; ++m) af[m]  = *(const short8*)&As[(wr * 64 + m * 16 + lr) * 32 + lh * 8];
#pragma unroll
        for (int n = 0; n < 4; ++n) bfr[n] = *(const short8*)&Bs[(wc * 64 + n * 16 + lr) * 32 + lh * 8];
#pragma unroll
        for (int m = 0; m < 4; ++m)
#pragma unroll
            for (int n = 0; n < 4; ++n)
                acc[m][n] = mfma16(af[m], bfr[n], acc[m][n]);
        __syncthreads();
    }

#pragma unroll
    for (int m = 0; m < 4; ++m)
#pragma unroll
        for (int n = 0; n < 4; ++n) {
            int row = row0 + wr * 64 + m * 16 + lh * 4;
            int col = col0 + wc * 64 + n * 16 + lr;
            float bv = BIAS ? bias[col] : 0.0f;
#pragma unroll
            for (int r = 0; r < 4; ++r) {
                size_t idx = (size_t)(row + r) * N + col;
                float v = acc[m][n][r] + bv;
                if (ACCUM) v += ((const float*)Cout)[idx];
                if (OUTBF16) ((unsigned short*)Cout)[idx] = f2b(v);
                else         ((float*)Cout)[idx] = v;
            }
        }
}

// ---------------- 5. per-(b,s,head) LN + RoPE on q,k ; copy v ----------------
__global__ __launch_bounds__(256) void qkv_prep(const unsigned short* __restrict__ fused,
                                                const float* __restrict__ qnw, const float* __restrict__ qnb,
                                                const float* __restrict__ knw, const float* __restrict__ knb,
                                                unsigned short* __restrict__ qf,
                                                unsigned short* __restrict__ kf,
                                                unsigned short* __restrict__ vf) {
    const int wid = threadIdx.x >> 6, lane = threadIdx.x & 63;
    const int job = blockIdx.x * 4 + wid;          // 0 .. B*S*HE-1
    const int srow = job / 12, h = job % 12;
    const int b = srow >> 11, s = srow & 2047;

    size_t base = (size_t)srow * N7 + C4 + h * HD;
    float qv = b2f(fused[base + lane]);
    float kv = b2f(fused[base + Cc + lane]);
    float vv = b2f(fused[base + 2 * Cc + lane]);

    float qs = qv, ks = kv;
#pragma unroll
    for (int m = 1; m < 64; m <<= 1) { qs += __shfl_xor(qs, m); ks += __shfl_xor(ks, m); }
    float qmu = qs * (1.0f / 64.0f), kmu = ks * (1.0f / 64.0f);
    float qd = qv - qmu, kd = kv - kmu;
    float qv2 = qd * qd, kv2 = kd * kd;
#pragma unroll
    for (int m = 1; m < 64; m <<= 1) { qv2 += __shfl_xor(qv2, m); kv2 += __shfl_xor(kv2, m); }
    float qn = qd * rsqrtf(qv2 * (1.0f / 64.0f) + 1e-5f) * qnw[lane] + qnb[lane];
    float kn = kd * rsqrtf(kv2 * (1.0f / 64.0f) + 1e-5f) * knw[lane] + knb[lane];

    if (lane < 48) {
        int axis = lane >> 4, ii = (lane & 15) >> 1;
        float basef = (1.0f + (float)ii * (127.0f / 7.0f)) * PI_F;
        int   pos_i = (axis == 0) ? (s >> 7) : (axis == 1) ? ((s >> 3) & 15) : (s & 7);
        float denom = (axis == 2) ? 7.0f : 15.0f;
        float pos   = -1.0f + 2.0f * (float)pos_i / denom;
        float ang   = pos * basef;
        float sn, cs;
        sincosf(ang, &sn, &cs);
        float qp = __shfl_xor(qn, 1);
        float kp = __shfl_xor(kn, 1);
        qn = (lane & 1) ? (qn * cs + qp * sn) : (qn * cs - qp * sn);
        kn = (lane & 1) ? (kn * cs + kp * sn) : (kn * cs - kp * sn);
    }

    size_t obase = ((size_t)(b * 12 + h) * Ss + s) * HD + lane;
    qf[obase] = f2b(qn);
    kf[obase] = f2b(kn);
    vf[obase] = f2b(vv);
}

// ---------------- 6. ffa = silu(gate) * xh ----------------
__global__ __launch_bounds__(256) void ffa_prep(const unsigned short* __restrict__ fused,
                                                unsigned short* __restrict__ ffa) {
    int i8 = blockIdx.x * 256 + threadIdx.x;
    int row = i8 / 192, co = (i8 % 192) * 8;
    U8 xa, ga, oa;
    xa.v = *(const uint4*)&fused[(size_t)row * N7 + co];
    ga.v = *(const uint4*)&fused[(size_t)row * N7 + C2 + co];
#pragma unroll
    for (int j = 0; j < 8; ++j) {
        float g = b2f(ga.u[j]);
        float xh = b2f(xa.u[j]);
        float sg = 1.0f / (1.0f + __expf(-g));
        oa.u[j] = f2b(g * sg * xh);
    }
    *(uint4*)&ffa[(size_t)row * C2 + co] = oa.v;
}

// ---------------- 7. flash attention, swizzled LDS ----------------
// Swizzle rule for Vt/Ps: element [row][col] stored at col-block (col>>3) ^ sw(row),
// so 8-elem fragment reads stay contiguous & 16B aligned (row stride 80 elems).
__global__ __launch_bounds__(256) void attn64(const unsigned short* __restrict__ qf,
                                              const unsigned short* __restrict__ kf,
                                              const unsigned short* __restrict__ vf,
                                              unsigned short* __restrict__ att) {
    __shared__ __align__(16) unsigned short Ks[64][80];
    __shared__ __align__(16) unsigned short Vt[64][80];   // Vt[d][key], key-block ^= (d>>3)&7
    __shared__ __align__(16) unsigned short Ps[4][16][80]; // Ps[w][q][key], key-block ^= (q>>2)&3
    const int tid = threadIdx.x, wid = tid >> 6, lane = tid & 63;
    const int lr = lane & 15, lh = lane >> 4;
    const int bh = blockIdx.y, qt = blockIdx.x;
    const int b = bh / 12, h = bh % 12;
    const size_t kvbase = (size_t)bh * Ss * HD;

    const int qrow = qt * 64 + wid * 16 + lr;
    short8 qa0 = *(const short8*)&qf[kvbase + (size_t)qrow * HD + lh * 8];
    short8 qa1 = *(const short8*)&qf[kvbase + (size_t)qrow * HD + 32 + lh * 8];

    float m_run[4] = {-1e30f, -1e30f, -1e30f, -1e30f};
    float l_run[4] = {0.f, 0.f, 0.f, 0.f};
    f32x4 oacc[4] = {};

    const int rxb = (lr >> 2) & 3;        // Ps read swizzle (row = lr)

    for (int kt = 0; kt < 32; ++kt) {
#pragma unroll
        for (int i = 0; i < 2; ++i) {
            int o = tid + i * 256;               // 0..511
            int r = o >> 3, kc = (o & 7) * 8;
            *(uint4*)&Ks[r][kc] = *(const uint4*)&kf[kvbase + (size_t)(kt * 64 + r) * HD + kc];
            U8 vv; vv.v = *(const uint4*)&vf[kvbase + (size_t)(kt * 64 + r) * HD + kc];
            int sv = (((r >> 3) ^ (kc >> 3)) << 3) | (r & 7);   // swizzled col for key=r, d-block=kc>>3
#pragma unroll
            for (int j = 0; j < 8; ++j) Vt[kc + j][sv] = vv.u[j];
        }
        __syncthreads();

        // scores: 16 q-rows x 64 keys per wave
        f32x4 sc[4];
#pragma unroll
        for (int n = 0; n < 4; ++n) {
            f32x4 z = {0.f, 0.f, 0.f, 0.f};
            short8 k0 = *(const short8*)&Ks[n * 16 + lr][lh * 8];
            short8 k1 = *(const short8*)&Ks[n * 16 + lr][32 + lh * 8];
            z = mfma16(qa0, k0, z);
            z = mfma16(qa1, k1, z);
            sc[n] = z;
        }

        // online softmax per row
#pragma unroll
        for (int r = 0; r < 4; ++r) {
            float s0 = sc[0][r] * 0.125f, s1 = sc[1][r] * 0.125f;
            float s2 = sc[2][r] * 0.125f, s3 = sc[3][r] * 0.125f;
            float tm = fmaxf(fmaxf(s0, s1), fmaxf(s2, s3));
#pragma unroll
            for (int mm = 1; mm < 16; mm <<= 1) tm = fmaxf(tm, __shfl_xor(tm, mm));
            float mnew = fmaxf(m_run[r], tm);
            float corr = __expf(m_run[r] - mnew);
            float p0 = __expf(s0 - mnew), p1 = __expf(s1 - mnew);
            float p2 = __expf(s2 - mnew), p3 = __expf(s3 - mnew);
            float ps = p0 + p1 + p2 + p3;
#pragma unroll
            for (int mm = 1; mm < 16; mm <<= 1) ps += __shfl_xor(ps, mm);
            l_run[r] = l_run[r] * corr + ps;
            m_run[r] = mnew;
#pragma unroll
            for (int n = 0; n < 4; ++n) oacc[n][r] *= corr;
            int prow = lh * 4 + r;
            int lo = lr & 7, lr3 = lr >> 3;
            Ps[wid][prow][(((0 + lr3) ^ lh) << 3) | lo] = f2bt(p0);   // key block 0+lr3
            Ps[wid][prow][(((2 + lr3) ^ lh) << 3) | lo] = f2bt(p1);   // key block 2+lr3
            Ps[wid][prow][(((4 + lr3) ^ lh) << 3) | lo] = f2bt(p2);
            Ps[wid][prow][(((6 + lr3) ^ lh) << 3) | lo] = f2bt(p3);
        }

        // PV: out(16x64) += P(16x64) @ V(64x64)
        short8 pa0 = *(const short8*)&Ps[wid][lr][((lh ^ rxb) & 7) * 8];
        short8 pa1 = *(const short8*)&Ps[wid][lr][(((lh + 4) ^ rxb) & 7) * 8];
#pragma unroll
        for (int n = 0; n < 4; ++n) {
            int dv = (2 * n + (lr >> 3)) & 7;   // (d>>3)&7 for d = n*16+lr
            short8 v0 = *(const short8*)&Vt[n * 16 + lr][((lh ^ dv) & 7) * 8];
            short8 v1 = *(const short8*)&Vt[n * 16 + lr][(((lh + 4) ^ dv) & 7) * 8];
            oacc[n] = mfma16(pa0, v0, oacc[n]);
            oacc[n] = mfma16(pa1, v1, oacc[n]);
        }
        __syncthreads();
    }

#pragma unroll
    for (int n = 0; n < 4; ++n)
#pragma unroll
        for (int r = 0; r < 4; ++r) {
            int srow_w = qt * 64 + wid * 16 + lh * 4 + r;
            int col = h * HD + n * 16 + lr;
            att[(size_t)(b * Ss + srow_w) * Cc + col] = f2b(oacc[n][r] / l_run[r]);
        }
}

// ---------------- 8. final: out = gamma*oacc^T + x ----------------
__global__ __launch_bounds__(256) void final_out(const float* __restrict__ oacc,
                                                 const float* __restrict__ x,
                                                 const float* __restrict__ gamma,
                                                 float* __restrict__ out) {
    __shared__ float tile[32][33];
    int b = blockIdx.z;
    int st = blockIdx.x * 32, ct = blockIdx.y * 32;
    int tx = threadIdx.x & 31, ty = threadIdx.x >> 5;
#pragma unroll
    for (int i = 0; i < 4; ++i) {
        int s = st + ty + i * 8;
        tile[ty + i * 8][tx] = oacc[(size_t)(b * Ss + s) * Cc + ct + tx];
    }
    __syncthreads();
#pragma unroll
    for (int i = 0; i < 4; ++i) {
        int c = ct + ty + i * 8;
        size_t idx = (size_t)(b * Cc + c) * Ss + st + tx;
        out[idx] = gamma[c] * tile[tx][ty + i * 8] + x[idx];
    }
}

// ---------------- host launch ----------------
extern "C" void kernel_launch(void* const* d_in, const int* in_sizes, int n_in,
                              void* d_out, int out_size, void* d_ws, size_t ws_size,
                              hipStream_t stream) {
    const float* x     = (const float*)d_in[0];
    const float* n1w   = (const float*)d_in[1];
    const float* n1b   = (const float*)d_in[2];
    const float* gamma = (const float*)d_in[3];
    const float* Wf    = (const float*)d_in[4];
    const float* bfu   = (const float*)d_in[5];
    const float* qnw   = (const float*)d_in[6];
    const float* qnb   = (const float*)d_in[7];
    const float* knw   = (const float*)d_in[8];
    const float* knb   = (const float*)d_in[9];
    const float* Wa    = (const float*)d_in[10];
    const float* Wo    = (const float*)d_in[11];
    const float* bo    = (const float*)d_in[12];

    char* ws = (char*)d_ws;
    size_t off = 0;
    auto alloc = [&](size_t bytes) {
        char* p = ws + off;
        off = (off + bytes + 255) & ~(size_t)255;
        return p;
    };
    float*          stat  = (float*)alloc(24 * 2 * 4);
    unsigned short* t     = (unsigned short*)alloc((size_t)BSr * Cc * 2);
    unsigned short* WtF   = (unsigned short*)alloc((size_t)N7 * Cc * 2);
    unsigned short* fused = (unsigned short*)alloc((size_t)BSr * N7 * 2);
    unsigned short* qfB   = (unsigned short*)alloc((size_t)Bb * HE * Ss * HD * 2);
    unsigned short* kfB   = (unsigned short*)alloc((size_t)Bb * HE * Ss * HD * 2);
    unsigned short* vfB   = (unsigned short*)alloc((size_t)Bb * HE * Ss * HD * 2);
    unsigned short* ffa   = (unsigned short*)alloc((size_t)BSr * C2 * 2);
    unsigned short* WtA   = (unsigned short*)alloc((size_t)Cc * Cc * 2);
    unsigned short* WtO   = (unsigned short*)alloc((size_t)Cc * C2 * 2);
    unsigned short* attB  = t;                       // alias (t dead by then)
    float*          oacc  = (float*)fused;           // alias (fused dead by then)

    transpose_w<<<dim3(N7 / 32, Cc / 32), 256, 0, stream>>>(Wf, WtF, Cc, N7);
    transpose_w<<<dim3(Cc / 32, Cc / 32), 256, 0, stream>>>(Wa, WtA, Cc, Cc);
    transpose_w<<<dim3(Cc / 32, C2 / 32), 256, 0, stream>>>(Wo, WtO, C2, Cc);

    gn_stats<<<24, 256, 0, stream>>>(x, stat);
    norm_transpose<<<dim3(Ss / 32, Cc / 32, Bb), 256, 0, stream>>>(x, stat, n1w, n1b, t);

    gemm128<false, true, true><<<dim3(N7 / 128, BSr / 128), 256, 0, stream>>>(
        t, WtF, bfu, fused, BSr, N7, Cc);

    qkv_prep<<<(Bb * Ss * HE) / 4, 256, 0, stream>>>(fused, qnw, qnb, knw, knb, qfB, kfB, vfB);
    ffa_prep<<<(BSr * C2 / 8) / 256, 256, 0, stream>>>(fused, ffa);

    attn64<<<dim3(Ss / 64, Bb * HE), 256, 0, stream>>>(qfB, kfB, vfB, attB);

    gemm128<false, false, false><<<dim3(Cc / 128, BSr / 128), 256, 0, stream>>>(
        attB, WtA, nullptr, oacc, BSr, Cc, Cc);
    gemm128<true, true, false><<<dim3(Cc / 128, BSr / 128), 256, 0, stream>>>(
        ffa, WtO, bo, oacc, BSr, Cc, C2);

    final_out<<<dim3(Ss / 32, Cc / 32, Bb), 256, 0, stream>>>(oacc, x, gamma, (float*)d_out);
}

// Round 6
// 387.949 us; speedup vs baseline: 1.2270x; 1.0807x over previous
//
#include <hip/hip_runtime.h>
#include <hip/hip_bf16.h>

// ---------------- problem constants ----------------
#define HE   12
#define HD   64
#define Cc   768
#define C2   1536
#define C4   3072
#define N7   5376
#define Bb   2
#define Ss   2048      // H*W*D = 16*16*8
#define BSr  4096      // B*S rows
#define PI_F 3.14159265358979f

using f32x4  = __attribute__((ext_vector_type(4))) float;
using short8 = __attribute__((ext_vector_type(8))) short;

__device__ __forceinline__ unsigned short f2b(float f) {
    union { float f; unsigned int u; } v; v.f = f;
    unsigned int u = v.u;
    unsigned int r = (u + 0x7fffu + ((u >> 16) & 1u)) >> 16;
    return (unsigned short)r;
}
__device__ __forceinline__ unsigned short f2bt(float f) {   // truncating
    union { float f; unsigned int u; } v; v.f = f;
    return (unsigned short)(v.u >> 16);
}
__device__ __forceinline__ float b2f(unsigned short s) {
    union { unsigned int u; float f; } v; v.u = ((unsigned int)s) << 16;
    return v.f;
}
__device__ __forceinline__ f32x4 mfma16(short8 a, short8 b, f32x4 c) {
    return __builtin_amdgcn_mfma_f32_16x16x32_bf16(a, b, c, 0, 0, 0);
}
// async global->LDS, 16 B per lane. LDS dest resolves to wave-uniform base + lane*16.
__device__ __forceinline__ void gl_lds16(const unsigned short* g, unsigned short* l) {
    __builtin_amdgcn_global_load_lds(
        (const __attribute__((address_space(1))) unsigned int*)(const void*)g,
        (__attribute__((address_space(3))) unsigned int*)(void*)l, 16, 0, 0);
}

union U8 { uint4 v; unsigned short u[8]; };

// ---------------- 1. tiled transpose f32 -> bf16 (weights) ----------------
__global__ __launch_bounds__(256) void transpose_w(const float* __restrict__ src,
                                                   unsigned short* __restrict__ dst,
                                                   int R, int Ccol) {
    __shared__ float tile[32][33];
    int tx = threadIdx.x & 31, ty = threadIdx.x >> 5;
    int rt = blockIdx.y * 32, ct = blockIdx.x * 32;
#pragma unroll
    for (int i = 0; i < 4; ++i)
        tile[ty + i * 8][tx] = src[(size_t)(rt + ty + i * 8) * Ccol + ct + tx];
    __syncthreads();
#pragma unroll
    for (int i = 0; i < 4; ++i)
        dst[(size_t)(ct + ty + i * 8) * R + rt + tx] = f2b(tile[tx][ty + i * 8]);
}

// ---------------- 2. groupnorm stats ----------------
__global__ __launch_bounds__(256) void gn_stats(const float* __restrict__ x,
                                                float* __restrict__ stat) {
    int j = blockIdx.x;
    const float4* p = (const float4*)(x + (size_t)j * 131072);
    float s = 0.f, ss = 0.f;
    for (int i = threadIdx.x; i < 32768; i += 256) {
        float4 v = p[i];
        s  += v.x + v.y + v.z + v.w;
        ss += v.x * v.x + v.y * v.y + v.z * v.z + v.w * v.w;
    }
#pragma unroll
    for (int m = 1; m < 64; m <<= 1) { s += __shfl_xor(s, m); ss += __shfl_xor(ss, m); }
    __shared__ float ls[4], lss[4];
    int wid = threadIdx.x >> 6;
    if ((threadIdx.x & 63) == 0) { ls[wid] = s; lss[wid] = ss; }
    __syncthreads();
    if (threadIdx.x == 0) {
        s = ls[0] + ls[1] + ls[2] + ls[3];
        ss = lss[0] + lss[1] + lss[2] + lss[3];
        float mu  = s / 131072.0f;
        float var = ss / 131072.0f - mu * mu;
        stat[j * 2]     = mu;
        stat[j * 2 + 1] = rsqrtf(var + 1e-5f);
    }
}

// ---------------- 3. normalize + transpose (B,C,S) -> t bf16 (B*S, C) ----------
__global__ __launch_bounds__(256) void norm_transpose(const float* __restrict__ x,
                                                      const float* __restrict__ stat,
                                                      const float* __restrict__ w,
                                                      const float* __restrict__ bgn,
                                                      unsigned short* __restrict__ t) {
    __shared__ float tile[32][33];
    int b = blockIdx.z;
    int st = blockIdx.x * 32, ct = blockIdx.y * 32;
    int tx = threadIdx.x & 31, ty = threadIdx.x >> 5;
#pragma unroll
    for (int i = 0; i < 4; ++i) {
        int c = ct + ty + i * 8;
        int g = c >> 6;
        float mu = stat[(b * 12 + g) * 2], rs = stat[(b * 12 + g) * 2 + 1];
        float v = x[(size_t)(b * Cc + c) * Ss + st + tx];
        tile[ty + i * 8][tx] = (v - mu) * rs * w[c] + bgn[c];
    }
    __syncthreads();
#pragma unroll
    for (int i = 0; i < 4; ++i) {
        int s = st + ty + i * 8, c = ct + tx;
        t[(size_t)(b * Ss + s) * Cc + c] = f2b(tile[tx][ty + i * 8]);
    }
}

// ---------------- 4. 128x128x32 bf16 MFMA GEMM, global_load_lds staging ---------
template<bool ACCUM, bool BIAS, bool OUTBF16>
__global__ __launch_bounds__(256) void gemm128(const unsigned short* __restrict__ A,
                                               const unsigned short* __restrict__ Bt,
                                               const float* __restrict__ bias,
                                               void* __restrict__ Cout,
                                               int M, int N, int K) {
    __shared__ __align__(16) unsigned short As[128 * 32];
    __shared__ __align__(16) unsigned short Bs[128 * 32];
    const int tid = threadIdx.x;
    const int wid = tid >> 6, lane = tid & 63;
    const int lr = lane & 15, lh = lane >> 4;
    const int wr = wid >> 1, wc = wid & 1;
    const int row0 = blockIdx.y * 128, col0 = blockIdx.x * 128;
    const unsigned short* ga = A  + (size_t)(row0 + (tid >> 2)) * K + (tid & 3) * 8;
    const unsigned short* gb = Bt + (size_t)(col0 + (tid >> 2)) * K + (tid & 3) * 8;
    f32x4 acc[4][4] = {};

    for (int k0 = 0; k0 < K; k0 += 32) {
        gl_lds16(ga + k0,          &As[tid * 8]);
        gl_lds16(ga + 64 * K + k0, &As[2048 + tid * 8]);
        gl_lds16(gb + k0,          &Bs[tid * 8]);
        gl_lds16(gb + 64 * K + k0, &Bs[2048 + tid * 8]);
        __syncthreads();
        short8 af[4], bfr[4];
#pragma unroll
        for (int m = 0; m < 4; ++m) af[m]  = *(const short8*)&As[(wr * 64 + m * 16 + lr) * 32 + lh * 8];
#pragma unroll
        for (int n = 0; n < 4; ++n) bfr[n] = *(const short8*)&Bs[(wc * 64 + n * 16 + lr) * 32 + lh * 8];
#pragma unroll
        for (int m = 0; m < 4; ++m)
#pragma unroll
            for (int n = 0; n < 4; ++n)
                acc[m][n] = mfma16(af[m], bfr[n], acc[m][n]);
        __syncthreads();
    }

#pragma unroll
    for (int m = 0; m < 4; ++m)
#pragma unroll
        for (int n = 0; n < 4; ++n) {
            int row = row0 + wr * 64 + m * 16 + lh * 4;
            int col = col0 + wc * 64 + n * 16 + lr;
            float bv = BIAS ? bias[col] : 0.0f;
#pragma unroll
            for (int r = 0; r < 4; ++r) {
                size_t idx = (size_t)(row + r) * N + col;
                float v = acc[m][n][r] + bv;
                if (ACCUM) v += ((const float*)Cout)[idx];
                if (OUTBF16) ((unsigned short*)Cout)[idx] = f2b(v);
                else         ((float*)Cout)[idx] = v;
            }
        }
}

// ---------------- 5. per-(b,s,head) LN + RoPE on q,k ; copy v ----------------
__global__ __launch_bounds__(256) void qkv_prep(const unsigned short* __restrict__ fused,
                                                const float* __restrict__ qnw, const float* __restrict__ qnb,
                                                const float* __restrict__ knw, const float* __restrict__ knb,
                                                unsigned short* __restrict__ qf,
                                                unsigned short* __restrict__ kf,
                                                unsigned short* __restrict__ vf) {
    const int wid = threadIdx.x >> 6, lane = threadIdx.x & 63;
    const int job = blockIdx.x * 4 + wid;
    const int srow = job / 12, h = job % 12;
    const int b = srow >> 11, s = srow & 2047;

    size_t base = (size_t)srow * N7 + C4 + h * HD;
    float qv = b2f(fused[base + lane]);
    float kv = b2f(fused[base + Cc + lane]);
    float vv = b2f(fused[base + 2 * Cc + lane]);

    float qs = qv, ks = kv;
#pragma unroll
    for (int m = 1; m < 64; m <<= 1) { qs += __shfl_xor(qs, m); ks += __shfl_xor(ks, m); }
    float qmu = qs * (1.0f / 64.0f), kmu = ks * (1.0f / 64.0f);
    float qd = qv - qmu, kd = kv - kmu;
    float qv2 = qd * qd, kv2 = kd * kd;
#pragma unroll
    for (int m = 1; m < 64; m <<= 1) { qv2 += __shfl_xor(qv2, m); kv2 += __shfl_xor(kv2, m); }
    float qn = qd * rsqrtf(qv2 * (1.0f / 64.0f) + 1e-5f) * qnw[lane] + qnb[lane];
    float kn = kd * rsqrtf(kv2 * (1.0f / 64.0f) + 1e-5f) * knw[lane] + knb[lane];

    if (lane < 48) {
        int axis = lane >> 4, ii = (lane & 15) >> 1;
        float basef = (1.0f + (float)ii * (127.0f / 7.0f)) * PI_F;
        int   pos_i = (axis == 0) ? (s >> 7) : (axis == 1) ? ((s >> 3) & 15) : (s & 7);
        float denom = (axis == 2) ? 7.0f : 15.0f;
        float pos   = -1.0f + 2.0f * (float)pos_i / denom;
        float ang   = pos * basef;
        float sn, cs;
        sincosf(ang, &sn, &cs);
        float qp = __shfl_xor(qn, 1);
        float kp = __shfl_xor(kn, 1);
        qn = (lane & 1) ? (qn * cs + qp * sn) : (qn * cs - qp * sn);
        kn = (lane & 1) ? (kn * cs + kp * sn) : (kn * cs - kp * sn);
    }

    size_t obase = ((size_t)(b * 12 + h) * Ss + s) * HD + lane;
    qf[obase] = f2b(qn);
    kf[obase] = f2b(kn);
    vf[obase] = f2b(vv);
}

// ---------------- 6. ffa = silu(gate) * xh ----------------
__global__ __launch_bounds__(256) void ffa_prep(const unsigned short* __restrict__ fused,
                                                unsigned short* __restrict__ ffa) {
    int i8 = blockIdx.x * 256 + threadIdx.x;
    int row = i8 / 192, co = (i8 % 192) * 8;
    U8 xa, ga, oa;
    xa.v = *(const uint4*)&fused[(size_t)row * N7 + co];
    ga.v = *(const uint4*)&fused[(size_t)row * N7 + C2 + co];
#pragma unroll
    for (int j = 0; j < 8; ++j) {
        float g = b2f(ga.u[j]);
        float xh = b2f(xa.u[j]);
        float sg = 1.0f / (1.0f + __expf(-g));
        oa.u[j] = f2b(g * sg * xh);
    }
    *(uint4*)&ffa[(size_t)row * C2 + co] = oa.v;
}

// ---------------- 7. flash attention: fixed-max softmax + ones-column l ---------
// Fixed max M=16 is exact here: |s| = |q.k|/8 <= |q||k|/8 ~ 8.3 (LN'd inputs),
// so p = exp(s-16) in [e^-25, e^-7]: no under/overflow, and p/sum(p) cancels scale.
// l computed via P @ ones with 2 extra MFMAs -> zero cross-lane ops in softmax.
__global__ __launch_bounds__(256) void attn64(const unsigned short* __restrict__ qf,
                                              const unsigned short* __restrict__ kf,
                                              const unsigned short* __restrict__ vf,
                                              unsigned short* __restrict__ att) {
    __shared__ __align__(16) unsigned short Ks[64][80];
    __shared__ __align__(16) unsigned short Vt[64][80];    // Vt[d][key], swizzled
    __shared__ __align__(16) unsigned short Ps[4][16][80]; // Ps[w][q][key], swizzled
    const int tid = threadIdx.x, wid = tid >> 6, lane = tid & 63;
    const int lr = lane & 15, lh = lane >> 4;
    const int bh = blockIdx.y, qt = blockIdx.x;
    const int b = bh / 12, h = bh % 12;
    const size_t kvbase = (size_t)bh * Ss * HD;

    const int qrow = qt * 64 + wid * 16 + lr;
    short8 qa0 = *(const short8*)&qf[kvbase + (size_t)qrow * HD + lh * 8];
    short8 qa1 = *(const short8*)&qf[kvbase + (size_t)qrow * HD + 32 + lh * 8];

    // staging geometry: this thread owns rows r0 and r0+32, d-cols kc0..kc0+7
    const int r0 = tid >> 3, kc0 = (tid & 7) * 8;
    const int sv0 = (((r0 >> 3) ^ (kc0 >> 3)) << 3) | (r0 & 7);
    const int sv1 = ((((r0 >> 3) + 4) ^ (kc0 >> 3)) << 3) | (r0 & 7);
    const unsigned short* kptr = kf + kvbase + (size_t)r0 * HD + kc0;
    const unsigned short* vptr = vf + kvbase + (size_t)r0 * HD + kc0;

    const short8 ones = {0x3F80, 0x3F80, 0x3F80, 0x3F80, 0x3F80, 0x3F80, 0x3F80, 0x3F80};
    const float c1 = 0.125f * 1.44269504f;     // scale * log2(e)
    const float c2 = 23.08312065f;             // 16 * log2(e)
    const int rxb = (lr >> 2) & 3;             // Ps read swizzle (row = lr)

    f32x4 oacc[4] = {};
    f32x4 lacc = {};

    // prologue: tile 0 into regs
    uint4 kreg0 = *(const uint4*)kptr;
    uint4 kreg1 = *(const uint4*)(kptr + 32 * HD);
    U8 vreg0, vreg1;
    vreg0.v = *(const uint4*)vptr;
    vreg1.v = *(const uint4*)(vptr + 32 * HD);

    for (int kt = 0; kt < 32; ++kt) {
        // write staged regs to LDS (prev compute finished at loop-bottom barrier)
        *(uint4*)&Ks[r0][kc0]      = kreg0;
        *(uint4*)&Ks[r0 + 32][kc0] = kreg1;
#pragma unroll
        for (int j = 0; j < 8; ++j) Vt[kc0 + j][sv0] = vreg0.u[j];
#pragma unroll
        for (int j = 0; j < 8; ++j) Vt[kc0 + j][sv1] = vreg1.u[j];
        __syncthreads();

        // issue next-tile loads; latency hides under QK + softmax + PV
        if (kt < 31) {
            const unsigned short* kp = kptr + (size_t)(kt + 1) * 64 * HD;
            const unsigned short* vp = vptr + (size_t)(kt + 1) * 64 * HD;
            kreg0 = *(const uint4*)kp;
            kreg1 = *(const uint4*)(kp + 32 * HD);
            vreg0.v = *(const uint4*)vp;
            vreg1.v = *(const uint4*)(vp + 32 * HD);
        }

        // scores: 16 q-rows x 64 keys per wave
        f32x4 sc[4];
#pragma unroll
        for (int n = 0; n < 4; ++n) {
            f32x4 z = {0.f, 0.f, 0.f, 0.f};
            short8 k0 = *(const short8*)&Ks[n * 16 + lr][lh * 8];
            short8 k1 = *(const short8*)&Ks[n * 16 + lr][32 + lh * 8];
            z = mfma16(qa0, k0, z);
            z = mfma16(qa1, k1, z);
            sc[n] = z;
        }

        // fixed-max softmax: p = exp2(s*c1 - c2), no reductions, no rescale
#pragma unroll
        for (int n = 0; n < 4; ++n)
#pragma unroll
            for (int r = 0; r < 4; ++r)
                sc[n][r] = exp2f(sc[n][r] * c1 - c2);

#pragma unroll
        for (int r = 0; r < 4; ++r) {
            int prow = lh * 4 + r;
            int lo = lr & 7, lr3 = lr >> 3;
            Ps[wid][prow][(((0 + lr3) ^ lh) << 3) | lo] = f2bt(sc[0][r]);
            Ps[wid][prow][(((2 + lr3) ^ lh) << 3) | lo] = f2bt(sc[1][r]);
            Ps[wid][prow][(((4 + lr3) ^ lh) << 3) | lo] = f2bt(sc[2][r]);
            Ps[wid][prow][(((6 + lr3) ^ lh) << 3) | lo] = f2bt(sc[3][r]);
        }

        // PV: out(16x64) += P(16x64) @ V(64x64) ; l += P @ ones
        short8 pa0 = *(const short8*)&Ps[wid][lr][((lh ^ rxb) & 7) * 8];
        short8 pa1 = *(const short8*)&Ps[wid][lr][(((lh + 4) ^ rxb) & 7) * 8];
        lacc = mfma16(pa0, ones, lacc);
        lacc = mfma16(pa1, ones, lacc);
#pragma unroll
        for (int n = 0; n < 4; ++n) {
            int dv = (2 * n + (lr >> 3)) & 7;
            short8 v0 = *(const short8*)&Vt[n * 16 + lr][((lh ^ dv) & 7) * 8];
            short8 v1 = *(const short8*)&Vt[n * 16 + lr][(((lh + 4) ^ dv) & 7) * 8];
            oacc[n] = mfma16(pa0, v0, oacc[n]);
            oacc[n] = mfma16(pa1, v1, oacc[n]);
        }
        __syncthreads();
    }

#pragma unroll
    for (int n = 0; n < 4; ++n)
#pragma unroll
        for (int r = 0; r < 4; ++r) {
            int srow_w = qt * 64 + wid * 16 + lh * 4 + r;
            int col = h * HD + n * 16 + lr;
            att[(size_t)(b * Ss + srow_w) * Cc + col] = f2b(oacc[n][r] / lacc[r]);
        }
}

// ---------------- 8. final: out = gamma*oacc^T + x ----------------
__global__ __launch_bounds__(256) void final_out(const float* __restrict__ oacc,
                                                 const float* __restrict__ x,
                                                 const float* __restrict__ gamma,
                                                 float* __restrict__ out) {
    __shared__ float tile[32][33];
    int b = blockIdx.z;
    int st = blockIdx.x * 32, ct = blockIdx.y * 32;
    int tx = threadIdx.x & 31, ty = threadIdx.x >> 5;
#pragma unroll
    for (int i = 0; i < 4; ++i) {
        int s = st + ty + i * 8;
        tile[ty + i * 8][tx] = oacc[(size_t)(b * Ss + s) * Cc + ct + tx];
    }
    __syncthreads();
#pragma unroll
    for (int i = 0; i < 4; ++i) {
        int c = ct + ty + i * 8;
        size_t idx = (size_t)(b * Cc + c) * Ss + st + tx;
        out[idx] = gamma[c] * tile[tx][ty + i * 8] + x[idx];
    }
}

// ---------------- host launch ----------------
extern "C" void kernel_launch(void* const* d_in, const int* in_sizes, int n_in,
                              void* d_out, int out_size, void* d_ws, size_t ws_size,
                              hipStream_t stream) {
    const float* x     = (const float*)d_in[0];
    const float* n1w   = (const float*)d_in[1];
    const float* n1b   = (const float*)d_in[2];
    const float* gamma = (const float*)d_in[3];
    const float* Wf    = (const float*)d_in[4];
    const float* bfu   = (const float*)d_in[5];
    const float* qnw   = (const float*)d_in[6];
    const float* qnb   = (const float*)d_in[7];
    const float* knw   = (const float*)d_in[8];
    const float* knb   = (const float*)d_in[9];
    const float* Wa    = (const float*)d_in[10];
    const float* Wo    = (const float*)d_in[11];
    const float* bo    = (const float*)d_in[12];

    char* ws = (char*)d_ws;
    size_t off = 0;
    auto alloc = [&](size_t bytes) {
        char* p = ws + off;
        off = (off + bytes + 255) & ~(size_t)255;
        return p;
    };
    float*          stat  = (float*)alloc(24 * 2 * 4);
    unsigned short* t     = (unsigned short*)alloc((size_t)BSr * Cc * 2);
    unsigned short* WtF   = (unsigned short*)alloc((size_t)N7 * Cc * 2);
    unsigned short* fused = (unsigned short*)alloc((size_t)BSr * N7 * 2);
    unsigned short* qfB   = (unsigned short*)alloc((size_t)Bb * HE * Ss * HD * 2);
    unsigned short* kfB   = (unsigned short*)alloc((size_t)Bb * HE * Ss * HD * 2);
    unsigned short* vfB   = (unsigned short*)alloc((size_t)Bb * HE * Ss * HD * 2);
    unsigned short* ffa   = (unsigned short*)alloc((size_t)BSr * C2 * 2);
    unsigned short* WtA   = (unsigned short*)alloc((size_t)Cc * Cc * 2);
    unsigned short* WtO   = (unsigned short*)alloc((size_t)Cc * C2 * 2);
    unsigned short* attB  = t;                       // alias (t dead by then)
    float*          oacc  = (float*)fused;           // alias (fused dead by then)

    transpose_w<<<dim3(N7 / 32, Cc / 32), 256, 0, stream>>>(Wf, WtF, Cc, N7);
    transpose_w<<<dim3(Cc / 32, Cc / 32), 256, 0, stream>>>(Wa, WtA, Cc, Cc);
    transpose_w<<<dim3(Cc / 32, C2 / 32), 256, 0, stream>>>(Wo, WtO, C2, Cc);

    gn_stats<<<24, 256, 0, stream>>>(x, stat);
    norm_transpose<<<dim3(Ss / 32, Cc / 32, Bb), 256, 0, stream>>>(x, stat, n1w, n1b, t);

    gemm128<false, true, true><<<dim3(N7 / 128, BSr / 128), 256, 0, stream>>>(
        t, WtF, bfu, fused, BSr, N7, Cc);

    qkv_prep<<<(Bb * Ss * HE) / 4, 256, 0, stream>>>(fused, qnw, qnb, knw, knb, qfB, kfB, vfB);
    ffa_prep<<<(BSr * C2 / 8) / 256, 256, 0, stream>>>(fused, ffa);

    attn64<<<dim3(Ss / 64, Bb * HE), 256, 0, stream>>>(qfB, kfB, vfB, attB);

    gemm128<false, false, false><<<dim3(Cc / 128, BSr / 128), 256, 0, stream>>>(
        attB, WtA, nullptr, oacc, BSr, Cc, Cc);
    gemm128<true, true, false><<<dim3(Cc / 128, BSr / 128), 256, 0, stream>>>(
        ffa, WtO, bo, oacc, BSr, Cc, C2);

    final_out<<<dim3(Ss / 32, Cc / 32, Bb), 256, 0, stream>>>(oacc, x, gamma, (float*)d_out);
}

// Round 7
// 370.793 us; speedup vs baseline: 1.2838x; 1.0463x over previous
//
#include <hip/hip_runtime.h>
#include <hip/hip_bf16.h>

// ---------------- problem constants ----------------
#define HE   12
#define HD   64
#define Cc   768
#define C2   1536
#define C4   3072
#define N7   5376
#define Bb   2
#define Ss   2048      // H*W*D = 16*16*8
#define BSr  4096      // B*S rows
#define PI_F 3.14159265358979f

using f32x4  = __attribute__((ext_vector_type(4))) float;
using short8 = __attribute__((ext_vector_type(8))) short;

__device__ __forceinline__ unsigned short f2b(float f) {
    union { float f; unsigned int u; } v; v.f = f;
    unsigned int u = v.u;
    unsigned int r = (u + 0x7fffu + ((u >> 16) & 1u)) >> 16;
    return (unsigned short)r;
}
__device__ __forceinline__ unsigned short f2bt(float f) {   // truncating
    union { float f; unsigned int u; } v; v.f = f;
    return (unsigned short)(v.u >> 16);
}
__device__ __forceinline__ float b2f(unsigned short s) {
    union { unsigned int u; float f; } v; v.u = ((unsigned int)s) << 16;
    return v.f;
}
__device__ __forceinline__ f32x4 mfma16(short8 a, short8 b, f32x4 c) {
    return __builtin_amdgcn_mfma_f32_16x16x32_bf16(a, b, c, 0, 0, 0);
}
// async global->LDS, 16 B per lane. LDS dest resolves to wave-uniform base + lane*16.
__device__ __forceinline__ void gl_lds16(const unsigned short* g, unsigned short* l) {
    __builtin_amdgcn_global_load_lds(
        (const __attribute__((address_space(1))) unsigned int*)(const void*)g,
        (__attribute__((address_space(3))) unsigned int*)(void*)l, 16, 0, 0);
}
// bijective XCD swizzle (requires nwg % 8 == 0)
__device__ __forceinline__ void xcd_tile(int& bx, int& by) {
    int nx = gridDim.x;
    int flat = blockIdx.y * nx + blockIdx.x;
    int nwg = nx * gridDim.y;
    int swz = (flat & 7) * (nwg >> 3) + (flat >> 3);
    bx = swz % nx; by = swz / nx;
}

union U8 { uint4 v; unsigned short u[8]; };

// ---------------- 1. tiled transpose f32 -> bf16 (weights) ----------------
__global__ __launch_bounds__(256) void transpose_w(const float* __restrict__ src,
                                                   unsigned short* __restrict__ dst,
                                                   int R, int Ccol) {
    __shared__ float tile[32][33];
    int tx = threadIdx.x & 31, ty = threadIdx.x >> 5;
    int rt = blockIdx.y * 32, ct = blockIdx.x * 32;
#pragma unroll
    for (int i = 0; i < 4; ++i)
        tile[ty + i * 8][tx] = src[(size_t)(rt + ty + i * 8) * Ccol + ct + tx];
    __syncthreads();
#pragma unroll
    for (int i = 0; i < 4; ++i)
        dst[(size_t)(ct + ty + i * 8) * R + rt + tx] = f2b(tile[tx][ty + i * 8]);
}

// ---------------- 2. groupnorm stats ----------------
__global__ __launch_bounds__(256) void gn_stats(const float* __restrict__ x,
                                                float* __restrict__ stat) {
    int j = blockIdx.x;
    const float4* p = (const float4*)(x + (size_t)j * 131072);
    float s = 0.f, ss = 0.f;
    for (int i = threadIdx.x; i < 32768; i += 256) {
        float4 v = p[i];
        s  += v.x + v.y + v.z + v.w;
        ss += v.x * v.x + v.y * v.y + v.z * v.z + v.w * v.w;
    }
#pragma unroll
    for (int m = 1; m < 64; m <<= 1) { s += __shfl_xor(s, m); ss += __shfl_xor(ss, m); }
    __shared__ float ls[4], lss[4];
    int wid = threadIdx.x >> 6;
    if ((threadIdx.x & 63) == 0) { ls[wid] = s; lss[wid] = ss; }
    __syncthreads();
    if (threadIdx.x == 0) {
        s = ls[0] + ls[1] + ls[2] + ls[3];
        ss = lss[0] + lss[1] + lss[2] + lss[3];
        float mu  = s / 131072.0f;
        float var = ss / 131072.0f - mu * mu;
        stat[j * 2]     = mu;
        stat[j * 2 + 1] = rsqrtf(var + 1e-5f);
    }
}

// ---------------- 3. normalize + transpose (B,C,S) -> t bf16 (B*S, C) ----------
__global__ __launch_bounds__(256) void norm_transpose(const float* __restrict__ x,
                                                      const float* __restrict__ stat,
                                                      const float* __restrict__ w,
                                                      const float* __restrict__ bgn,
                                                      unsigned short* __restrict__ t) {
    __shared__ float tile[32][33];
    int b = blockIdx.z;
    int st = blockIdx.x * 32, ct = blockIdx.y * 32;
    int tx = threadIdx.x & 31, ty = threadIdx.x >> 5;
#pragma unroll
    for (int i = 0; i < 4; ++i) {
        int c = ct + ty + i * 8;
        int g = c >> 6;
        float mu = stat[(b * 12 + g) * 2], rs = stat[(b * 12 + g) * 2 + 1];
        float v = x[(size_t)(b * Cc + c) * Ss + st + tx];
        tile[ty + i * 8][tx] = (v - mu) * rs * w[c] + bgn[c];
    }
    __syncthreads();
#pragma unroll
    for (int i = 0; i < 4; ++i) {
        int s = st + ty + i * 8, c = ct + tx;
        t[(size_t)(b * Ss + s) * Cc + c] = f2b(tile[tx][ty + i * 8]);
    }
}

// ---------------- 4. 128x128x32 bf16 MFMA GEMM, global_load_lds staging ---------
template<bool ACCUM, bool BIAS, bool OUTBF16>
__global__ __launch_bounds__(256) void gemm128(const unsigned short* __restrict__ A,
                                               const unsigned short* __restrict__ Bt,
                                               const float* __restrict__ bias,
                                               void* __restrict__ Cout,
                                               int M, int N, int K) {
    __shared__ __align__(16) unsigned short As[128 * 32];
    __shared__ __align__(16) unsigned short Bs[128 * 32];
    const int tid = threadIdx.x;
    const int wid = tid >> 6, lane = tid & 63;
    const int lr = lane & 15, lh = lane >> 4;
    const int wr = wid >> 1, wc = wid & 1;
    int bx, by; xcd_tile(bx, by);
    const int row0 = by * 128, col0 = bx * 128;
    const unsigned short* ga = A  + (size_t)(row0 + (tid >> 2)) * K + (tid & 3) * 8;
    const unsigned short* gb = Bt + (size_t)(col0 + (tid >> 2)) * K + (tid & 3) * 8;
    f32x4 acc[4][4] = {};

    for (int k0 = 0; k0 < K; k0 += 32) {
        gl_lds16(ga + k0,          &As[tid * 8]);
        gl_lds16(ga + 64 * K + k0, &As[2048 + tid * 8]);
        gl_lds16(gb + k0,          &Bs[tid * 8]);
        gl_lds16(gb + 64 * K + k0, &Bs[2048 + tid * 8]);
        __syncthreads();
        short8 af[4], bfr[4];
#pragma unroll
        for (int m = 0; m < 4; ++m) af[m]  = *(const short8*)&As[(wr * 64 + m * 16 + lr) * 32 + lh * 8];
#pragma unroll
        for (int n = 0; n < 4; ++n) bfr[n] = *(const short8*)&Bs[(wc * 64 + n * 16 + lr) * 32 + lh * 8];
#pragma unroll
        for (int m = 0; m < 4; ++m)
#pragma unroll
            for (int n = 0; n < 4; ++n)
                acc[m][n] = mfma16(af[m], bfr[n], acc[m][n]);
        __syncthreads();
    }

#pragma unroll
    for (int m = 0; m < 4; ++m)
#pragma unroll
        for (int n = 0; n < 4; ++n) {
            int row = row0 + wr * 64 + m * 16 + lh * 4;
            int col = col0 + wc * 64 + n * 16 + lr;
            float bv = BIAS ? bias[col] : 0.0f;
#pragma unroll
            for (int r = 0; r < 4; ++r) {
                size_t idx = (size_t)(row + r) * N + col;
                float v = acc[m][n][r] + bv;
                if (ACCUM) v += ((const float*)Cout)[idx];
                if (OUTBF16) ((unsigned short*)Cout)[idx] = f2b(v);
                else         ((float*)Cout)[idx] = v;
            }
        }
}

// ---- 4b. final GEMM: oacc-accumulate + gamma/residual/transpose epilogue ------
// out(B,C,S) = gamma[col] * (A@Bt^T + bo[col] + oaccIn) + x   ; M rows = b*Ss+s
__global__ __launch_bounds__(256) void gemm_fin(const unsigned short* __restrict__ A,
                                                const unsigned short* __restrict__ Bt,
                                                const float* __restrict__ bo,
                                                const float* __restrict__ oaccIn,
                                                const float* __restrict__ x,
                                                const float* __restrict__ gamma,
                                                float* __restrict__ out,
                                                int M, int N, int K) {
    __shared__ __align__(16) unsigned short As[128 * 32];
    __shared__ __align__(16) unsigned short Bs[128 * 32];
    const int tid = threadIdx.x;
    const int wid = tid >> 6, lane = tid & 63;
    const int lr = lane & 15, lh = lane >> 4;
    const int wr = wid >> 1, wc = wid & 1;
    int bx, by; xcd_tile(bx, by);
    const int row0 = by * 128, col0 = bx * 128;
    const unsigned short* ga = A  + (size_t)(row0 + (tid >> 2)) * K + (tid & 3) * 8;
    const unsigned short* gb = Bt + (size_t)(col0 + (tid >> 2)) * K + (tid & 3) * 8;
    f32x4 acc[4][4] = {};

    for (int k0 = 0; k0 < K; k0 += 32) {
        gl_lds16(ga + k0,          &As[tid * 8]);
        gl_lds16(ga + 64 * K + k0, &As[2048 + tid * 8]);
        gl_lds16(gb + k0,          &Bs[tid * 8]);
        gl_lds16(gb + 64 * K + k0, &Bs[2048 + tid * 8]);
        __syncthreads();
        short8 af[4], bfr[4];
#pragma unroll
        for (int m = 0; m < 4; ++m) af[m]  = *(const short8*)&As[(wr * 64 + m * 16 + lr) * 32 + lh * 8];
#pragma unroll
        for (int n = 0; n < 4; ++n) bfr[n] = *(const short8*)&Bs[(wc * 64 + n * 16 + lr) * 32 + lh * 8];
#pragma unroll
        for (int m = 0; m < 4; ++m)
#pragma unroll
            for (int n = 0; n < 4; ++n)
                acc[m][n] = mfma16(af[m], bfr[n], acc[m][n]);
        __syncthreads();
    }

#pragma unroll
    for (int m = 0; m < 4; ++m)
#pragma unroll
        for (int n = 0; n < 4; ++n) {
            int row = row0 + wr * 64 + m * 16 + lh * 4;
            int col = col0 + wc * 64 + n * 16 + lr;
            float bv = bo[col], gv = gamma[col];
#pragma unroll
            for (int r = 0; r < 4; ++r) {
                int rw = row + r;
                float v = acc[m][n][r] + bv + oaccIn[(size_t)rw * N + col];
                int b = rw >> 11, s = rw & 2047;
                size_t oidx = (size_t)(b * Cc + col) * Ss + s;
                out[oidx] = gv * v + x[oidx];
            }
        }
}

// ---------------- 5. per-(b,s,head) LN + RoPE on q,k ; copy v ----------------
__global__ __launch_bounds__(256) void qkv_prep(const unsigned short* __restrict__ fused,
                                                const float* __restrict__ qnw, const float* __restrict__ qnb,
                                                const float* __restrict__ knw, const float* __restrict__ knb,
                                                unsigned short* __restrict__ qf,
                                                unsigned short* __restrict__ kf,
                                                unsigned short* __restrict__ vf) {
    const int wid = threadIdx.x >> 6, lane = threadIdx.x & 63;
    const int job = blockIdx.x * 4 + wid;
    const int srow = job / 12, h = job % 12;
    const int b = srow >> 11, s = srow & 2047;

    size_t base = (size_t)srow * N7 + C4 + h * HD;
    float qv = b2f(fused[base + lane]);
    float kv = b2f(fused[base + Cc + lane]);
    float vv = b2f(fused[base + 2 * Cc + lane]);

    float qs = qv, ks = kv;
#pragma unroll
    for (int m = 1; m < 64; m <<= 1) { qs += __shfl_xor(qs, m); ks += __shfl_xor(ks, m); }
    float qmu = qs * (1.0f / 64.0f), kmu = ks * (1.0f / 64.0f);
    float qd = qv - qmu, kd = kv - kmu;
    float qv2 = qd * qd, kv2 = kd * kd;
#pragma unroll
    for (int m = 1; m < 64; m <<= 1) { qv2 += __shfl_xor(qv2, m); kv2 += __shfl_xor(kv2, m); }
    float qn = qd * rsqrtf(qv2 * (1.0f / 64.0f) + 1e-5f) * qnw[lane] + qnb[lane];
    float kn = kd * rsqrtf(kv2 * (1.0f / 64.0f) + 1e-5f) * knw[lane] + knb[lane];

    if (lane < 48) {
        int axis = lane >> 4, ii = (lane & 15) >> 1;
        float basef = (1.0f + (float)ii * (127.0f / 7.0f)) * PI_F;
        int   pos_i = (axis == 0) ? (s >> 7) : (axis == 1) ? ((s >> 3) & 15) : (s & 7);
        float denom = (axis == 2) ? 7.0f : 15.0f;
        float pos   = -1.0f + 2.0f * (float)pos_i / denom;
        float ang   = pos * basef;
        float sn, cs;
        sincosf(ang, &sn, &cs);
        float qp = __shfl_xor(qn, 1);
        float kp = __shfl_xor(kn, 1);
        qn = (lane & 1) ? (qn * cs + qp * sn) : (qn * cs - qp * sn);
        kn = (lane & 1) ? (kn * cs + kp * sn) : (kn * cs - kp * sn);
    }

    size_t obase = ((size_t)(b * 12 + h) * Ss + s) * HD + lane;
    qf[obase] = f2b(qn);
    kf[obase] = f2b(kn);
    vf[obase] = f2b(vv);
}

// ---------------- 6. ffa = silu(gate) * xh ----------------
__global__ __launch_bounds__(256) void ffa_prep(const unsigned short* __restrict__ fused,
                                                unsigned short* __restrict__ ffa) {
    int i8 = blockIdx.x * 256 + threadIdx.x;
    int row = i8 / 192, co = (i8 % 192) * 8;
    U8 xa, ga, oa;
    xa.v = *(const uint4*)&fused[(size_t)row * N7 + co];
    ga.v = *(const uint4*)&fused[(size_t)row * N7 + C2 + co];
#pragma unroll
    for (int j = 0; j < 8; ++j) {
        float g = b2f(ga.u[j]);
        float xh = b2f(xa.u[j]);
        float sg = 1.0f / (1.0f + __expf(-g));
        oa.u[j] = f2b(g * sg * xh);
    }
    *(uint4*)&ffa[(size_t)row * C2 + co] = oa.v;
}

// ---------------- 7. flash attention: fixed-max softmax, double-buffered LDS ----
// Fixed max M=16 is exact here (LN'd q,k: |s|<=~8.3); l via P@ones MFMA.
// Single barrier per KV-tile: iter t writes tile t+1 into buf^1, computes t.
__global__ __launch_bounds__(256) void attn64(const unsigned short* __restrict__ qf,
                                              const unsigned short* __restrict__ kf,
                                              const unsigned short* __restrict__ vf,
                                              unsigned short* __restrict__ att) {
    __shared__ __align__(16) unsigned short Ks[2][64][80];
    __shared__ __align__(16) unsigned short Vt[2][64][80];   // Vt[d][key], swizzled
    __shared__ __align__(16) unsigned short Ps[4][16][80];   // wave-private
    const int tid = threadIdx.x, wid = tid >> 6, lane = tid & 63;
    const int lr = lane & 15, lh = lane >> 4;
    const int bh = blockIdx.y, qt = blockIdx.x;
    const int b = bh / 12, h = bh % 12;
    const size_t kvbase = (size_t)bh * Ss * HD;

    const int qrow = qt * 64 + wid * 16 + lr;
    short8 qa0 = *(const short8*)&qf[kvbase + (size_t)qrow * HD + lh * 8];
    short8 qa1 = *(const short8*)&qf[kvbase + (size_t)qrow * HD + 32 + lh * 8];

    // staging geometry: this thread owns rows r0 and r0+32, d-cols kc0..kc0+7
    const int r0 = tid >> 3, kc0 = (tid & 7) * 8;
    const int sv0 = (((r0 >> 3) ^ (kc0 >> 3)) << 3) | (r0 & 7);
    const int sv1 = ((((r0 >> 3) + 4) ^ (kc0 >> 3)) << 3) | (r0 & 7);
    const unsigned short* kptr = kf + kvbase + (size_t)r0 * HD + kc0;
    const unsigned short* vptr = vf + kvbase + (size_t)r0 * HD + kc0;

    const short8 ones = {0x3F80, 0x3F80, 0x3F80, 0x3F80, 0x3F80, 0x3F80, 0x3F80, 0x3F80};
    const float c1 = 0.125f * 1.44269504f;     // scale * log2(e)
    const float c2 = 23.08312065f;             // 16 * log2(e)
    const int rxb = (lr >> 2) & 3;             // Ps read swizzle (row = lr)

    f32x4 oacc[4] = {};
    f32x4 lacc = {};

    // prologue: tile 0 -> buf0; tile 1 -> regs
    uint4 kreg0 = *(const uint4*)kptr;
    uint4 kreg1 = *(const uint4*)(kptr + 32 * HD);
    U8 vreg0, vreg1;
    vreg0.v = *(const uint4*)vptr;
    vreg1.v = *(const uint4*)(vptr + 32 * HD);
    *(uint4*)&Ks[0][r0][kc0]      = kreg0;
    *(uint4*)&Ks[0][r0 + 32][kc0] = kreg1;
#pragma unroll
    for (int j = 0; j < 8; ++j) Vt[0][kc0 + j][sv0] = vreg0.u[j];
#pragma unroll
    for (int j = 0; j < 8; ++j) Vt[0][kc0 + j][sv1] = vreg1.u[j];
    kreg0   = *(const uint4*)(kptr + 64 * HD);
    kreg1   = *(const uint4*)(kptr + 96 * HD);
    vreg0.v = *(const uint4*)(vptr + 64 * HD);
    vreg1.v = *(const uint4*)(vptr + 96 * HD);
    __syncthreads();

#pragma unroll 2
    for (int kt = 0; kt < 32; ++kt) {
        const int cur = kt & 1;
        // write staged regs (tile kt+1) into the other buffer
        if (kt < 31) {
            *(uint4*)&Ks[cur ^ 1][r0][kc0]      = kreg0;
            *(uint4*)&Ks[cur ^ 1][r0 + 32][kc0] = kreg1;
#pragma unroll
            for (int j = 0; j < 8; ++j) Vt[cur ^ 1][kc0 + j][sv0] = vreg0.u[j];
#pragma unroll
            for (int j = 0; j < 8; ++j) Vt[cur ^ 1][kc0 + j][sv1] = vreg1.u[j];
        }
        // issue loads for tile kt+2 (consumed next iteration)
        if (kt < 30) {
            const unsigned short* kp = kptr + (size_t)(kt + 2) * 64 * HD;
            const unsigned short* vp = vptr + (size_t)(kt + 2) * 64 * HD;
            kreg0   = *(const uint4*)kp;
            kreg1   = *(const uint4*)(kp + 32 * HD);
            vreg0.v = *(const uint4*)vp;
            vreg1.v = *(const uint4*)(vp + 32 * HD);
        }

        // scores: 16 q-rows x 64 keys per wave
        f32x4 sc[4];
#pragma unroll
        for (int n = 0; n < 4; ++n) {
            f32x4 z = {0.f, 0.f, 0.f, 0.f};
            short8 k0 = *(const short8*)&Ks[cur][n * 16 + lr][lh * 8];
            short8 k1 = *(const short8*)&Ks[cur][n * 16 + lr][32 + lh * 8];
            z = mfma16(qa0, k0, z);
            z = mfma16(qa1, k1, z);
            sc[n] = z;
        }

        // fixed-max softmax: p = exp2(s*c1 - c2), no reductions, no rescale
#pragma unroll
        for (int n = 0; n < 4; ++n)
#pragma unroll
            for (int r = 0; r < 4; ++r)
                sc[n][r] = exp2f(sc[n][r] * c1 - c2);

#pragma unroll
        for (int r = 0; r < 4; ++r) {
            int prow = lh * 4 + r;
            int lo = lr & 7, lr3 = lr >> 3;
            Ps[wid][prow][(((0 + lr3) ^ lh) << 3) | lo] = f2bt(sc[0][r]);
            Ps[wid][prow][(((2 + lr3) ^ lh) << 3) | lo] = f2bt(sc[1][r]);
            Ps[wid][prow][(((4 + lr3) ^ lh) << 3) | lo] = f2bt(sc[2][r]);
            Ps[wid][prow][(((6 + lr3) ^ lh) << 3) | lo] = f2bt(sc[3][r]);
        }

        // PV: out(16x64) += P(16x64) @ V(64x64) ; l += P @ ones
        short8 pa0 = *(const short8*)&Ps[wid][lr][((lh ^ rxb) & 7) * 8];
        short8 pa1 = *(const short8*)&Ps[wid][lr][(((lh + 4) ^ rxb) & 7) * 8];
        lacc = mfma16(pa0, ones, lacc);
        lacc = mfma16(pa1, ones, lacc);
#pragma unroll
        for (int n = 0; n < 4; ++n) {
            int dv = (2 * n + (lr >> 3)) & 7;
            short8 v0 = *(const short8*)&Vt[cur][n * 16 + lr][((lh ^ dv) & 7) * 8];
            short8 v1 = *(const short8*)&Vt[cur][n * 16 + lr][(((lh + 4) ^ dv) & 7) * 8];
            oacc[n] = mfma16(pa0, v0, oacc[n]);
            oacc[n] = mfma16(pa1, v1, oacc[n]);
        }
        __syncthreads();
    }

    float rinv[4];
#pragma unroll
    for (int r = 0; r < 4; ++r) rinv[r] = 1.0f / lacc[r];
#pragma unroll
    for (int n = 0; n < 4; ++n)
#pragma unroll
        for (int r = 0; r < 4; ++r) {
            int srow_w = qt * 64 + wid * 16 + lh * 4 + r;
            int col = h * HD + n * 16 + lr;
            att[(size_t)(b * Ss + srow_w) * Cc + col] = f2b(oacc[n][r] * rinv[r]);
        }
}

// ---------------- host launch ----------------
extern "C" void kernel_launch(void* const* d_in, const int* in_sizes, int n_in,
                              void* d_out, int out_size, void* d_ws, size_t ws_size,
                              hipStream_t stream) {
    const float* x     = (const float*)d_in[0];
    const float* n1w   = (const float*)d_in[1];
    const float* n1b   = (const float*)d_in[2];
    const float* gamma = (const float*)d_in[3];
    const float* Wf    = (const float*)d_in[4];
    const float* bfu   = (const float*)d_in[5];
    const float* qnw   = (const float*)d_in[6];
    const float* qnb   = (const float*)d_in[7];
    const float* knw   = (const float*)d_in[8];
    const float* knb   = (const float*)d_in[9];
    const float* Wa    = (const float*)d_in[10];
    const float* Wo    = (const float*)d_in[11];
    const float* bo    = (const float*)d_in[12];

    char* ws = (char*)d_ws;
    size_t off = 0;
    auto alloc = [&](size_t bytes) {
        char* p = ws + off;
        off = (off + bytes + 255) & ~(size_t)255;
        return p;
    };
    float*          stat  = (float*)alloc(24 * 2 * 4);
    unsigned short* t     = (unsigned short*)alloc((size_t)BSr * Cc * 2);
    unsigned short* WtF   = (unsigned short*)alloc((size_t)N7 * Cc * 2);
    unsigned short* fused = (unsigned short*)alloc((size_t)BSr * N7 * 2);
    unsigned short* qfB   = (unsigned short*)alloc((size_t)Bb * HE * Ss * HD * 2);
    unsigned short* kfB   = (unsigned short*)alloc((size_t)Bb * HE * Ss * HD * 2);
    unsigned short* vfB   = (unsigned short*)alloc((size_t)Bb * HE * Ss * HD * 2);
    unsigned short* ffa   = (unsigned short*)alloc((size_t)BSr * C2 * 2);
    unsigned short* WtA   = (unsigned short*)alloc((size_t)Cc * Cc * 2);
    unsigned short* WtO   = (unsigned short*)alloc((size_t)Cc * C2 * 2);
    unsigned short* attB  = t;                       // alias (t dead by then)
    float*          oacc  = (float*)fused;           // alias (fused dead by then)

    transpose_w<<<dim3(N7 / 32, Cc / 32), 256, 0, stream>>>(Wf, WtF, Cc, N7);
    transpose_w<<<dim3(Cc / 32, Cc / 32), 256, 0, stream>>>(Wa, WtA, Cc, Cc);
    transpose_w<<<dim3(Cc / 32, C2 / 32), 256, 0, stream>>>(Wo, WtO, C2, Cc);

    gn_stats<<<24, 256, 0, stream>>>(x, stat);
    norm_transpose<<<dim3(Ss / 32, Cc / 32, Bb), 256, 0, stream>>>(x, stat, n1w, n1b, t);

    gemm128<false, true, true><<<dim3(N7 / 128, BSr / 128), 256, 0, stream>>>(
        t, WtF, bfu, fused, BSr, N7, Cc);

    qkv_prep<<<(Bb * Ss * HE) / 4, 256, 0, stream>>>(fused, qnw, qnb, knw, knb, qfB, kfB, vfB);
    ffa_prep<<<(BSr * C2 / 8) / 256, 256, 0, stream>>>(fused, ffa);

    attn64<<<dim3(Ss / 64, Bb * HE), 256, 0, stream>>>(qfB, kfB, vfB, attB);

    // oacc = att @ W_attn  (f32)
    gemm128<false, false, false><<<dim3(Cc / 128, BSr / 128), 256, 0, stream>>>(
        attB, WtA, nullptr, oacc, BSr, Cc, Cc);
    // out = gamma * (ffa @ W_ffout + bo + oacc) + x   (fused epilogue, transposed store)
    gemm_fin<<<dim3(Cc / 128, BSr / 128), 256, 0, stream>>>(
        ffa, WtO, bo, oacc, x, gamma, (float*)d_out, BSr, Cc, C2);
}